// Round 4
// baseline (1531.796 us; speedup 1.0000x reference)
//
#include <hip/hip_runtime.h>
#include <hip/hip_fp16.h>

#define NODES 100000
#define DIM 128
#define KSTEPS 10
#define CAP 128          // fixed CSR slot capacity; max in-degree ~Poisson(32) -> ~65 max

// Block-aggregated binning: NR coarse ranges of RANGE nodes.
#define RSHIFT 11
#define RANGE 2048                   // nodes per range (CSR window = 1 MB, L2-resident)
#define NR 49                        // ceil(100000/2048)
#define GBCAP 72000                  // mean E/NR ~65.3K, sigma ~254 -> +26 sigma headroom
#define VPT 16                       // edges per thread per batch
#define BT (256 * VPT)               // 4096 edges per block-batch

// ---------- build phase A: block-aggregated two-stream binning ----------
__global__ void bucket_agg(const int* __restrict__ src, const int* __restrict__ dst,
                           unsigned* __restrict__ gdc, unsigned* __restrict__ gsc,
                           unsigned* __restrict__ dpairs, unsigned* __restrict__ spairs, int E) {
    __shared__ unsigned dcnt[NR], scnt[NR], dbase[NR], sbase[NR];
    const int tid = threadIdx.x;
    if (tid < NR) { dcnt[tid] = 0; scnt[tid] = 0; }
    __syncthreads();

    const int base = blockIdx.x * BT;
    int dv[VPT], sv[VPT];
    unsigned rd[VPT], rs[VPT];
    #pragma unroll
    for (int j = 0; j < VPT; ++j) {
        int i = base + tid + j * 256;
        if (i < E) {
            int d_ = dst[i]; int s_ = src[i];
            dv[j] = d_; sv[j] = s_;
            rd[j] = atomicAdd(&dcnt[d_ >> RSHIFT], 1u);
            rs[j] = atomicAdd(&scnt[s_ >> RSHIFT], 1u);
        }
    }
    __syncthreads();
    if (tid < NR) {
        unsigned c = dcnt[tid];
        dbase[tid] = c ? atomicAdd(&gdc[tid], c) : 0u;
    } else if (tid >= 64 && tid < 64 + NR) {
        int b = tid - 64;
        unsigned c = scnt[b];
        sbase[b] = c ? atomicAdd(&gsc[b], c) : 0u;
    }
    __syncthreads();
    #pragma unroll
    for (int j = 0; j < VPT; ++j) {
        int i = base + tid + j * 256;
        if (i < E) {
            int d_ = dv[j]; int s_ = sv[j];
            int b = d_ >> RSHIFT;
            unsigned pos = dbase[b] + rd[j];
            if (pos < GBCAP)
                dpairs[(size_t)b * GBCAP + pos] =
                    ((unsigned)s_ << RSHIFT) | (unsigned)(d_ & (RANGE - 1));
            int bs = s_ >> RSHIFT;
            unsigned ps = sbase[bs] + rs[j];
            if (ps < GBCAP)
                spairs[(size_t)bs * GBCAP + ps] = (unsigned)(s_ & (RANGE - 1));
        }
    }
}

// ---------- build phase B: per-range CSR scatter + degrees, LDS counters only ----------
__global__ void degree_scatter(const unsigned* __restrict__ gdc, const unsigned* __restrict__ gsc,
                               const unsigned* __restrict__ dpairs, const unsigned* __restrict__ spairs,
                               int* __restrict__ cur, int* __restrict__ outc,
                               int* __restrict__ csr) {
    __shared__ int ctr[RANGE];
    const int r = blockIdx.x >> 1;
    const int nodebase = r << RSHIFT;
    for (int i = threadIdx.x; i < RANGE; i += blockDim.x) ctr[i] = 0;
    __syncthreads();
    if ((blockIdx.x & 1) == 0) {
        int cnt = (int)gdc[r]; if (cnt > GBCAP) cnt = GBCAP;
        const unsigned* p = dpairs + (size_t)r * GBCAP;
        for (int i = threadIdx.x; i < cnt; i += blockDim.x) {
            unsigned v = p[i];
            int dloc = (int)(v & (RANGE - 1));
            int s_ = (int)(v >> RSHIFT);
            int slot = atomicAdd(&ctr[dloc], 1);
            if (slot < CAP) csr[((size_t)(nodebase + dloc) << 7) + slot] = s_;
        }
        __syncthreads();
        for (int i = threadIdx.x; i < RANGE; i += blockDim.x) {
            int node = nodebase + i;
            if (node < NODES) cur[node] = ctr[i];
        }
    } else {
        int cnt = (int)gsc[r]; if (cnt > GBCAP) cnt = GBCAP;
        const unsigned* p = spairs + (size_t)r * GBCAP;
        for (int i = threadIdx.x; i < cnt; i += blockDim.x)
            atomicAdd(&ctr[p[i]], 1);
        __syncthreads();
        for (int i = threadIdx.x; i < RANGE; i += blockDim.x) {
            int node = nodebase + i;
            if (node < NODES) outc[node] = ctr[i];
        }
    }
}

// norms: src_norm = rsqrt(max(outdeg,1)); isrc = 1/src_norm; dst_norm = rsqrt(max(indeg,1))
__global__ void norm_kernel(const int* __restrict__ outc, const int* __restrict__ inc,
                            float* __restrict__ src_norm, float* __restrict__ isrc,
                            float* __restrict__ dst_norm, int n) {
    int i = blockIdx.x * blockDim.x + threadIdx.x;
    if (i < n) {
        float od = fmaxf((float)outc[i], 1.0f);
        float id = fmaxf((float)inc[i], 1.0f);
        float sn = rsqrtf(od);
        src_norm[i] = sn;
        isrc[i] = sqrtf(od);
        dst_norm[i] = rsqrtf(id);
    }
}

// ring path k=0: sg0 = sigmoid(<feats,s>); p0 = src_norm * feats (fp16). No out write.
__global__ void combine0_main(const float* __restrict__ feats, const float* __restrict__ s,
                              const float* __restrict__ src_norm,
                              __half* __restrict__ p0, float* __restrict__ sg0, int n) {
    int lane = threadIdx.x & 63;
    int wave = (blockIdx.x * blockDim.x + threadIdx.x) >> 6;
    int nwaves = (gridDim.x * blockDim.x) >> 6;
    float2 sv = *(const float2*)(s + lane * 2);
    for (int node = wave; node < n; node += nwaves) {
        float2 hv = *(const float2*)(feats + (size_t)node * DIM + lane * 2);
        float sn = src_norm[node];
        __half2 ph; ph.x = __float2half(sn * hv.x); ph.y = __float2half(sn * hv.y);
        *(__half2*)(p0 + (size_t)node * DIM + lane * 2) = ph;
        float dot = hv.x * sv.x + hv.y * sv.y;
        #pragma unroll
        for (int off = 32; off > 0; off >>= 1) dot += __shfl_xor(dot, off);
        if (lane == 0) sg0[node] = 1.0f / (1.0f + expf(-dot));
    }
}

// fallback k=0: out = sigmoid(<feats,s>)*feats; p0 = src_norm*feats
__global__ void combine0_fb(const float* __restrict__ feats, const float* __restrict__ s,
                            const float* __restrict__ src_norm,
                            __half* __restrict__ p0, float* __restrict__ out, int n) {
    int lane = threadIdx.x & 63;
    int wave = (blockIdx.x * blockDim.x + threadIdx.x) >> 6;
    int nwaves = (gridDim.x * blockDim.x) >> 6;
    float2 sv = *(const float2*)(s + lane * 2);
    for (int node = wave; node < n; node += nwaves) {
        float2 hv = *(const float2*)(feats + (size_t)node * DIM + lane * 2);
        float sn = src_norm[node];
        __half2 ph; ph.x = __float2half(sn * hv.x); ph.y = __float2half(sn * hv.y);
        *(__half2*)(p0 + (size_t)node * DIM + lane * 2) = ph;
        float dot = hv.x * sv.x + hv.y * sv.y;
        #pragma unroll
        for (int off = 32; off > 0; off >>= 1) dot += __shfl_xor(dot, off);
        float sg = 1.0f / (1.0f + expf(-dot));
        float2 ov; ov.x = sg * hv.x; ov.y = sg * hv.y;
        *(float2*)(out + (size_t)node * DIM + lane * 2) = ov;
    }
}

// One wave per node. raw = sum_{e in slots} p_prev[src_e]; h = dst_norm*raw;
// sg_k[n] = sigmoid(<h,s>); p_next = src_norm*h (fp16). No out access.
__global__ void gather_main(const __half* __restrict__ pprev,
                            const float* __restrict__ src_norm, const float* __restrict__ dst_norm,
                            const int* __restrict__ cnt, const int* __restrict__ csr,
                            const float* __restrict__ s,
                            __half* __restrict__ pnext, float* __restrict__ sgk, int n) {
    int lane = threadIdx.x & 63;
    int wave = (blockIdx.x * blockDim.x + threadIdx.x) >> 6;
    int nwaves = (gridDim.x * blockDim.x) >> 6;
    float2 sv = *(const float2*)(s + lane * 2);
    for (int node = wave; node < n; node += nwaves) {
        int c = cnt[node]; if (c > CAP) c = CAP;
        const int* row = csr + ((size_t)node << 7);
        float accx = 0.0f, accy = 0.0f;
        int p = 0;
        for (; p + 7 < c; p += 8) {
            int s0 = row[p], s1 = row[p+1], s2 = row[p+2], s3 = row[p+3];
            int s4 = row[p+4], s5 = row[p+5], s6 = row[p+6], s7 = row[p+7];
            float2 f0 = __half22float2(*(const __half2*)(pprev + (size_t)s0 * DIM + lane * 2));
            float2 f1 = __half22float2(*(const __half2*)(pprev + (size_t)s1 * DIM + lane * 2));
            float2 f2 = __half22float2(*(const __half2*)(pprev + (size_t)s2 * DIM + lane * 2));
            float2 f3 = __half22float2(*(const __half2*)(pprev + (size_t)s3 * DIM + lane * 2));
            float2 f4 = __half22float2(*(const __half2*)(pprev + (size_t)s4 * DIM + lane * 2));
            float2 f5 = __half22float2(*(const __half2*)(pprev + (size_t)s5 * DIM + lane * 2));
            float2 f6 = __half22float2(*(const __half2*)(pprev + (size_t)s6 * DIM + lane * 2));
            float2 f7 = __half22float2(*(const __half2*)(pprev + (size_t)s7 * DIM + lane * 2));
            accx += f0.x + f1.x + f2.x + f3.x + f4.x + f5.x + f6.x + f7.x;
            accy += f0.y + f1.y + f2.y + f3.y + f4.y + f5.y + f6.y + f7.y;
        }
        for (; p < c; ++p) {
            int si = row[p];
            float2 fv = __half22float2(*(const __half2*)(pprev + (size_t)si * DIM + lane * 2));
            accx += fv.x; accy += fv.y;
        }
        float dn = dst_norm[node];
        float hx = dn * accx, hy = dn * accy;
        float dot = hx * sv.x + hy * sv.y;
        #pragma unroll
        for (int off = 32; off > 0; off >>= 1) dot += __shfl_xor(dot, off);
        if (lane == 0) sgk[node] = 1.0f / (1.0f + expf(-dot));
        float sn = src_norm[node];
        __half2 pw; pw.x = __float2half(sn * hx); pw.y = __float2half(sn * hy);
        *(__half2*)(pnext + (size_t)node * DIM + lane * 2) = pw;
    }
}

// fallback: same gather, but out += sg*h in-loop, no sg storage
__global__ void gather_fb(const __half* __restrict__ pprev,
                          const float* __restrict__ src_norm, const float* __restrict__ dst_norm,
                          const int* __restrict__ cnt, const int* __restrict__ csr,
                          const float* __restrict__ s,
                          __half* __restrict__ pnext, float* __restrict__ out, int n) {
    int lane = threadIdx.x & 63;
    int wave = (blockIdx.x * blockDim.x + threadIdx.x) >> 6;
    int nwaves = (gridDim.x * blockDim.x) >> 6;
    float2 sv = *(const float2*)(s + lane * 2);
    for (int node = wave; node < n; node += nwaves) {
        int c = cnt[node]; if (c > CAP) c = CAP;
        const int* row = csr + ((size_t)node << 7);
        float accx = 0.0f, accy = 0.0f;
        int p = 0;
        for (; p + 7 < c; p += 8) {
            int s0 = row[p], s1 = row[p+1], s2 = row[p+2], s3 = row[p+3];
            int s4 = row[p+4], s5 = row[p+5], s6 = row[p+6], s7 = row[p+7];
            float2 f0 = __half22float2(*(const __half2*)(pprev + (size_t)s0 * DIM + lane * 2));
            float2 f1 = __half22float2(*(const __half2*)(pprev + (size_t)s1 * DIM + lane * 2));
            float2 f2 = __half22float2(*(const __half2*)(pprev + (size_t)s2 * DIM + lane * 2));
            float2 f3 = __half22float2(*(const __half2*)(pprev + (size_t)s3 * DIM + lane * 2));
            float2 f4 = __half22float2(*(const __half2*)(pprev + (size_t)s4 * DIM + lane * 2));
            float2 f5 = __half22float2(*(const __half2*)(pprev + (size_t)s5 * DIM + lane * 2));
            float2 f6 = __half22float2(*(const __half2*)(pprev + (size_t)s6 * DIM + lane * 2));
            float2 f7 = __half22float2(*(const __half2*)(pprev + (size_t)s7 * DIM + lane * 2));
            accx += f0.x + f1.x + f2.x + f3.x + f4.x + f5.x + f6.x + f7.x;
            accy += f0.y + f1.y + f2.y + f3.y + f4.y + f5.y + f6.y + f7.y;
        }
        for (; p < c; ++p) {
            int si = row[p];
            float2 fv = __half22float2(*(const __half2*)(pprev + (size_t)si * DIM + lane * 2));
            accx += fv.x; accy += fv.y;
        }
        float dn = dst_norm[node];
        float hx = dn * accx, hy = dn * accy;
        float dot = hx * sv.x + hy * sv.y;
        #pragma unroll
        for (int off = 32; off > 0; off >>= 1) dot += __shfl_xor(dot, off);
        float sg = 1.0f / (1.0f + expf(-dot));
        float2 ov = *(float2*)(out + (size_t)node * DIM + lane * 2);
        ov.x += sg * hx; ov.y += sg * hy;
        *(float2*)(out + (size_t)node * DIM + lane * 2) = ov;
        float sn = src_norm[node];
        __half2 pw; pw.x = __float2half(sn * hx); pw.y = __float2half(sn * hy);
        *(__half2*)(pnext + (size_t)node * DIM + lane * 2) = pw;
    }
}

// flush: out[n] (+)= sum_{j=0..count-1} sg_{kstart+j}[n] * isrc[n] * p_{(kstart+j)%m}[n]
__global__ void out_accum(const __half* __restrict__ pbase, const float* __restrict__ sg,
                          const float* __restrict__ isrc, float* __restrict__ out,
                          int kstart, int count, int m, int first, int n) {
    int lane = threadIdx.x & 63;
    int wave = (blockIdx.x * blockDim.x + threadIdx.x) >> 6;
    int nwaves = (gridDim.x * blockDim.x) >> 6;
    for (int node = wave; node < n; node += nwaves) {
        float iv = isrc[node];
        float ax, ay;
        if (first) { ax = 0.0f; ay = 0.0f; }
        else {
            float2 ov = *(float2*)(out + (size_t)node * DIM + lane * 2);
            ax = ov.x; ay = ov.y;
        }
        for (int j = 0; j < count; ++j) {
            int kk = kstart + j;
            int slot = kk % m;
            float g = sg[(size_t)kk * n + node] * iv;
            float2 fv = __half22float2(
                *(const __half2*)(pbase + ((size_t)slot * n + node) * DIM + lane * 2));
            ax += g * fv.x; ay += g * fv.y;
        }
        *(float2*)(out + (size_t)node * DIM + lane * 2) = make_float2(ax, ay);
    }
}

extern "C" void kernel_launch(void* const* d_in, const int* in_sizes, int n_in,
                              void* d_out, int out_size, void* d_ws, size_t ws_size,
                              hipStream_t stream) {
    const float* feats = (const float*)d_in[0];
    const float* s     = (const float*)d_in[1];
    const int*   src   = (const int*)d_in[2];
    const int*   dst   = (const int*)d_in[3];
    float* out = (float*)d_out;
    const int E = in_sizes[2];

    // Workspace layout
    int*   outc     = (int*)d_ws;                         // N
    int*   cur      = outc + NODES;                       // N (in-degree after build)
    float* src_norm = (float*)(cur + NODES);              // N
    float* isrc     = src_norm + NODES;                   // N
    float* dst_norm = isrc + NODES;                       // N
    float* sg       = dst_norm + NODES;                   // 11*N
    int*   csr      = (int*)(sg + (size_t)(KSTEPS + 1) * NODES);   // N*CAP
    __half* pbase   = (__half*)(csr + (size_t)NODES * CAP);

    const size_t head_bytes = (size_t)(2 * NODES) * 4 + (size_t)(3 + KSTEPS + 1) * NODES * 4
                            + (size_t)NODES * CAP * 4;
    const size_t pbuf = (size_t)NODES * DIM * sizeof(__half);   // 25.6 MB each

    // Ring size: how many p-slabs fit in the remaining workspace.
    int m = 0;
    if (ws_size > head_bytes) m = (int)((ws_size - head_bytes) / pbuf);
    if (m > KSTEPS + 1) m = KSTEPS + 1;

    // Bucket storage aliased over the first p-slabs (28.2 MB spans p0 + 2.6 MB
    // of p1). Both are first written by combine0/gather(k=1) AFTER the build
    // completes (stream-ordered) -> aliasing is safe.
    unsigned* gdc    = (unsigned*)pbase;
    unsigned* gsc    = gdc + 64;
    unsigned* dpairs = gsc + 64;
    unsigned* spairs = dpairs + (size_t)NR * GBCAP;

    hipMemsetAsync(gdc, 0, 2 * 64 * sizeof(unsigned), stream);
    const int nbatch = (E + BT - 1) / BT;
    bucket_agg<<<nbatch, 256, 0, stream>>>(src, dst, gdc, gsc, dpairs, spairs, E);
    degree_scatter<<<2 * NR, 256, 0, stream>>>(gdc, gsc, dpairs, spairs, cur, outc, csr);
    norm_kernel<<<(NODES + 255) / 256, 256, 0, stream>>>(outc, cur, src_norm, isrc, dst_norm, NODES);

    const int ngrid = (NODES * 64 + 255) / 256;
    if (m >= 2) {
        // Slab ring of size m: p_k lives in slot k%m. Flush out += sg*isrc*p
        // whenever the next gather would overwrite an unflushed slab.
        combine0_main<<<ngrid, 256, 0, stream>>>(feats, s, src_norm, pbase, sg, NODES);
        int flushed = 0;    // ks [0, flushed) already folded into out
        int first = 1;
        for (int k = 1; k <= KSTEPS; ++k) {
            if (k - flushed >= m) {
                out_accum<<<ngrid, 256, 0, stream>>>(pbase, sg, isrc, out,
                                                     flushed, k - flushed, m, first, NODES);
                flushed = k; first = 0;
            }
            const __half* pprev = pbase + (size_t)((k - 1) % m) * NODES * DIM;
            __half* pnext = pbase + (size_t)(k % m) * NODES * DIM;
            gather_main<<<ngrid, 256, 0, stream>>>(pprev, src_norm, dst_norm, cur, csr, s,
                                                   pnext, sg + (size_t)k * NODES, NODES);
        }
        out_accum<<<ngrid, 256, 0, stream>>>(pbase, sg, isrc, out,
                                             flushed, KSTEPS + 1 - flushed, m, first, NODES);
    } else {
        // Emergency fallback (should not trigger: ring-2 fits wherever the old
        // double-buffer fallback fit).
        __half* pA = pbase;
        __half* pB = pbase + (size_t)NODES * DIM;
        combine0_fb<<<ngrid, 256, 0, stream>>>(feats, s, src_norm, pA, out, NODES);
        const __half* pcur = pA;
        for (int k = 1; k <= KSTEPS; ++k) {
            __half* pnext = (k & 1) ? pB : pA;
            gather_fb<<<ngrid, 256, 0, stream>>>(pcur, src_norm, dst_norm, cur, csr, s,
                                                 pnext, out, NODES);
            pcur = pnext;
        }
    }
}

// Round 5
// 1414.196 us; speedup vs baseline: 1.0832x; 1.0832x over previous
//
#include <hip/hip_runtime.h>
#include <hip/hip_fp16.h>

#define NODES 100000
#define DIM 128
#define KSTEPS 10
#define CAP 96           // CSR slot capacity; max in-degree ~Poisson(32), max ~65 (<11 sigma)

// Block-aggregated binning: NR coarse ranges of RANGE nodes.
#define RSHIFT 11
#define RANGE 2048                   // nodes per range (CSR window L2-resident)
#define NR 49                        // ceil(100000/2048)
#define GBCAP 72000                  // mean E/NR ~65.3K -> +26 sigma headroom
#define VPT 16                       // edges per thread per batch
#define BT (256 * VPT)               // 4096 edges per block-batch

// Slab stride: NODES rows + 1 zero sentinel row (for padded-CSR gather).
#define SLAB ((size_t)(NODES + 1) * DIM)

// ---------- build phase A: block-aggregated two-stream binning ----------
__global__ void bucket_agg(const int* __restrict__ src, const int* __restrict__ dst,
                           unsigned* __restrict__ gdc, unsigned* __restrict__ gsc,
                           unsigned* __restrict__ dpairs, unsigned* __restrict__ spairs, int E) {
    __shared__ unsigned dcnt[NR], scnt[NR], dbase[NR], sbase[NR];
    const int tid = threadIdx.x;
    if (tid < NR) { dcnt[tid] = 0; scnt[tid] = 0; }
    __syncthreads();

    const int base = blockIdx.x * BT;
    int dv[VPT], sv[VPT];
    unsigned rd[VPT], rs[VPT];
    #pragma unroll
    for (int j = 0; j < VPT; ++j) {
        int i = base + tid + j * 256;
        if (i < E) {
            int d_ = dst[i]; int s_ = src[i];
            dv[j] = d_; sv[j] = s_;
            rd[j] = atomicAdd(&dcnt[d_ >> RSHIFT], 1u);
            rs[j] = atomicAdd(&scnt[s_ >> RSHIFT], 1u);
        }
    }
    __syncthreads();
    if (tid < NR) {
        unsigned c = dcnt[tid];
        dbase[tid] = c ? atomicAdd(&gdc[tid], c) : 0u;
    } else if (tid >= 64 && tid < 64 + NR) {
        int b = tid - 64;
        unsigned c = scnt[b];
        sbase[b] = c ? atomicAdd(&gsc[b], c) : 0u;
    }
    __syncthreads();
    #pragma unroll
    for (int j = 0; j < VPT; ++j) {
        int i = base + tid + j * 256;
        if (i < E) {
            int d_ = dv[j]; int s_ = sv[j];
            int b = d_ >> RSHIFT;
            unsigned pos = dbase[b] + rd[j];
            if (pos < GBCAP)
                dpairs[(size_t)b * GBCAP + pos] =
                    ((unsigned)s_ << RSHIFT) | (unsigned)(d_ & (RANGE - 1));
            int bs = s_ >> RSHIFT;
            unsigned ps = sbase[bs] + rs[j];
            if (ps < GBCAP)
                spairs[(size_t)bs * GBCAP + ps] = (unsigned)(s_ & (RANGE - 1));
        }
    }
}

// ---------- build phase B: per-range CSR scatter + degrees, LDS counters only ----------
// dst part additionally pads each CSR row to a multiple of 8 with sentinel
// index NODES (points at a zeroed row in every p-slab) -> branch-free gather.
__global__ void degree_scatter(const unsigned* __restrict__ gdc, const unsigned* __restrict__ gsc,
                               const unsigned* __restrict__ dpairs, const unsigned* __restrict__ spairs,
                               int* __restrict__ cur, int* __restrict__ outc,
                               int* __restrict__ csr) {
    __shared__ int ctr[RANGE];
    const int r = blockIdx.x >> 1;
    const int nodebase = r << RSHIFT;
    for (int i = threadIdx.x; i < RANGE; i += blockDim.x) ctr[i] = 0;
    __syncthreads();
    if ((blockIdx.x & 1) == 0) {
        int cnt = (int)gdc[r]; if (cnt > GBCAP) cnt = GBCAP;
        const unsigned* p = dpairs + (size_t)r * GBCAP;
        for (int i = threadIdx.x; i < cnt; i += blockDim.x) {
            unsigned v = p[i];
            int dloc = (int)(v & (RANGE - 1));
            int s_ = (int)(v >> RSHIFT);
            int slot = atomicAdd(&ctr[dloc], 1);
            if (slot < CAP) csr[(size_t)(nodebase + dloc) * CAP + slot] = s_;
        }
        __syncthreads();
        for (int i = threadIdx.x; i < RANGE; i += blockDim.x) {
            int node = nodebase + i;
            if (node < NODES) {
                int c = ctr[i]; if (c > CAP) c = CAP;
                cur[node] = ctr[i];
                int cpad = (c + 7) & ~7; if (cpad > CAP) cpad = CAP;
                for (int q = c; q < cpad; ++q)
                    csr[(size_t)node * CAP + q] = NODES;   // sentinel -> zero row
            }
        }
    } else {
        int cnt = (int)gsc[r]; if (cnt > GBCAP) cnt = GBCAP;
        const unsigned* p = spairs + (size_t)r * GBCAP;
        for (int i = threadIdx.x; i < cnt; i += blockDim.x)
            atomicAdd(&ctr[p[i]], 1);
        __syncthreads();
        for (int i = threadIdx.x; i < RANGE; i += blockDim.x) {
            int node = nodebase + i;
            if (node < NODES) outc[node] = ctr[i];
        }
    }
}

// norms: src_norm = rsqrt(max(outdeg,1)); isrc = 1/src_norm; dst_norm = rsqrt(max(indeg,1))
__global__ void norm_kernel(const int* __restrict__ outc, const int* __restrict__ inc,
                            float* __restrict__ src_norm, float* __restrict__ isrc,
                            float* __restrict__ dst_norm, int n) {
    int i = blockIdx.x * blockDim.x + threadIdx.x;
    if (i < n) {
        float od = fmaxf((float)outc[i], 1.0f);
        float id = fmaxf((float)inc[i], 1.0f);
        float sn = rsqrtf(od);
        src_norm[i] = sn;
        isrc[i] = sqrtf(od);
        dst_norm[i] = rsqrtf(id);
    }
}

// ring path k=0: sg0 = sigmoid(<feats,s>); p0 = src_norm * feats (fp16). No out write.
__global__ void combine0_main(const float* __restrict__ feats, const float* __restrict__ s,
                              const float* __restrict__ src_norm,
                              __half* __restrict__ p0, float* __restrict__ sg0, int n) {
    int lane = threadIdx.x & 63;
    int wave = (blockIdx.x * blockDim.x + threadIdx.x) >> 6;
    int nwaves = (gridDim.x * blockDim.x) >> 6;
    float2 sv = *(const float2*)(s + lane * 2);
    for (int node = wave; node < n; node += nwaves) {
        float2 hv = *(const float2*)(feats + (size_t)node * DIM + lane * 2);
        float sn = src_norm[node];
        __half2 ph; ph.x = __float2half(sn * hv.x); ph.y = __float2half(sn * hv.y);
        *(__half2*)(p0 + (size_t)node * DIM + lane * 2) = ph;
        float dot = hv.x * sv.x + hv.y * sv.y;
        #pragma unroll
        for (int off = 32; off > 0; off >>= 1) dot += __shfl_xor(dot, off);
        if (lane == 0) sg0[node] = 1.0f / (1.0f + expf(-dot));
    }
}

// fallback k=0: out = sigmoid(<feats,s>)*feats; p0 = src_norm*feats
__global__ void combine0_fb(const float* __restrict__ feats, const float* __restrict__ s,
                            const float* __restrict__ src_norm,
                            __half* __restrict__ p0, float* __restrict__ out, int n) {
    int lane = threadIdx.x & 63;
    int wave = (blockIdx.x * blockDim.x + threadIdx.x) >> 6;
    int nwaves = (gridDim.x * blockDim.x) >> 6;
    float2 sv = *(const float2*)(s + lane * 2);
    for (int node = wave; node < n; node += nwaves) {
        float2 hv = *(const float2*)(feats + (size_t)node * DIM + lane * 2);
        float sn = src_norm[node];
        __half2 ph; ph.x = __float2half(sn * hv.x); ph.y = __float2half(sn * hv.y);
        *(__half2*)(p0 + (size_t)node * DIM + lane * 2) = ph;
        float dot = hv.x * sv.x + hv.y * sv.y;
        #pragma unroll
        for (int off = 32; off > 0; off >>= 1) dot += __shfl_xor(dot, off);
        float sg = 1.0f / (1.0f + expf(-dot));
        float2 ov; ov.x = sg * hv.x; ov.y = sg * hv.y;
        *(float2*)(out + (size_t)node * DIM + lane * 2) = ov;
    }
}

// One wave per node, 4-rows-per-instruction gather.
// Lane layout: g = lane>>4 (edge sub-group), t = lane&15 (dims 8t..8t+7).
// Each uint4 load = 16 B = 8 halves of one row; one wave instruction covers
// 4 rows (1 KB). CSR rows are padded to a multiple of 8 with sentinel NODES
// (zero row) so the loop is branch-free.
__global__ void gather_main(const __half* __restrict__ pprev,
                            const float* __restrict__ src_norm, const float* __restrict__ dst_norm,
                            const int* __restrict__ cnt, const int* __restrict__ csr,
                            const float* __restrict__ s,
                            __half* __restrict__ pnext, float* __restrict__ sgk, int n) {
    int lane = threadIdx.x & 63;
    int g = lane >> 4, t = lane & 15;
    int wave = (blockIdx.x * blockDim.x + threadIdx.x) >> 6;
    int nwaves = (gridDim.x * blockDim.x) >> 6;
    float4 sva = *(const float4*)(s + t * 8);
    float4 svb = *(const float4*)(s + t * 8 + 4);
    for (int node = wave; node < n; node += nwaves) {
        int c = cnt[node]; if (c > CAP) c = CAP;
        int cpad = (c + 7) & ~7;
        const int* row = csr + (size_t)node * CAP;
        float a0=0,a1=0,a2=0,a3=0,a4=0,a5=0,a6=0,a7=0;
        int p = 0;
        for (; p + 15 < cpad; p += 16) {
            int e0 = row[p + g];
            int e1 = row[p + 4 + g];
            int e2 = row[p + 8 + g];
            int e3 = row[p + 12 + g];
            uint4 q0 = *(const uint4*)(pprev + (size_t)e0 * DIM + t * 8);
            uint4 q1 = *(const uint4*)(pprev + (size_t)e1 * DIM + t * 8);
            uint4 q2 = *(const uint4*)(pprev + (size_t)e2 * DIM + t * 8);
            uint4 q3 = *(const uint4*)(pprev + (size_t)e3 * DIM + t * 8);
            float2 f;
            f = __half22float2(*(__half2*)&q0.x); a0+=f.x; a1+=f.y;
            f = __half22float2(*(__half2*)&q0.y); a2+=f.x; a3+=f.y;
            f = __half22float2(*(__half2*)&q0.z); a4+=f.x; a5+=f.y;
            f = __half22float2(*(__half2*)&q0.w); a6+=f.x; a7+=f.y;
            f = __half22float2(*(__half2*)&q1.x); a0+=f.x; a1+=f.y;
            f = __half22float2(*(__half2*)&q1.y); a2+=f.x; a3+=f.y;
            f = __half22float2(*(__half2*)&q1.z); a4+=f.x; a5+=f.y;
            f = __half22float2(*(__half2*)&q1.w); a6+=f.x; a7+=f.y;
            f = __half22float2(*(__half2*)&q2.x); a0+=f.x; a1+=f.y;
            f = __half22float2(*(__half2*)&q2.y); a2+=f.x; a3+=f.y;
            f = __half22float2(*(__half2*)&q2.z); a4+=f.x; a5+=f.y;
            f = __half22float2(*(__half2*)&q2.w); a6+=f.x; a7+=f.y;
            f = __half22float2(*(__half2*)&q3.x); a0+=f.x; a1+=f.y;
            f = __half22float2(*(__half2*)&q3.y); a2+=f.x; a3+=f.y;
            f = __half22float2(*(__half2*)&q3.z); a4+=f.x; a5+=f.y;
            f = __half22float2(*(__half2*)&q3.w); a6+=f.x; a7+=f.y;
        }
        for (; p < cpad; p += 8) {
            int e0 = row[p + g];
            int e1 = row[p + 4 + g];
            uint4 q0 = *(const uint4*)(pprev + (size_t)e0 * DIM + t * 8);
            uint4 q1 = *(const uint4*)(pprev + (size_t)e1 * DIM + t * 8);
            float2 f;
            f = __half22float2(*(__half2*)&q0.x); a0+=f.x; a1+=f.y;
            f = __half22float2(*(__half2*)&q0.y); a2+=f.x; a3+=f.y;
            f = __half22float2(*(__half2*)&q0.z); a4+=f.x; a5+=f.y;
            f = __half22float2(*(__half2*)&q0.w); a6+=f.x; a7+=f.y;
            f = __half22float2(*(__half2*)&q1.x); a0+=f.x; a1+=f.y;
            f = __half22float2(*(__half2*)&q1.y); a2+=f.x; a3+=f.y;
            f = __half22float2(*(__half2*)&q1.z); a4+=f.x; a5+=f.y;
            f = __half22float2(*(__half2*)&q1.w); a6+=f.x; a7+=f.y;
        }
        // fold the 4 edge sub-groups (lane bits 4,5)
        a0 += __shfl_xor(a0, 16); a0 += __shfl_xor(a0, 32);
        a1 += __shfl_xor(a1, 16); a1 += __shfl_xor(a1, 32);
        a2 += __shfl_xor(a2, 16); a2 += __shfl_xor(a2, 32);
        a3 += __shfl_xor(a3, 16); a3 += __shfl_xor(a3, 32);
        a4 += __shfl_xor(a4, 16); a4 += __shfl_xor(a4, 32);
        a5 += __shfl_xor(a5, 16); a5 += __shfl_xor(a5, 32);
        a6 += __shfl_xor(a6, 16); a6 += __shfl_xor(a6, 32);
        a7 += __shfl_xor(a7, 16); a7 += __shfl_xor(a7, 32);
        float dn = dst_norm[node];
        float h0=dn*a0, h1=dn*a1, h2=dn*a2, h3=dn*a3;
        float h4=dn*a4, h5=dn*a5, h6=dn*a6, h7=dn*a7;
        float dot = h0*sva.x + h1*sva.y + h2*sva.z + h3*sva.w
                  + h4*svb.x + h5*svb.y + h6*svb.z + h7*svb.w;
        dot += __shfl_xor(dot, 1); dot += __shfl_xor(dot, 2);
        dot += __shfl_xor(dot, 4); dot += __shfl_xor(dot, 8);
        if (lane == 0) sgk[node] = 1.0f / (1.0f + expf(-dot));
        float sn = src_norm[node];
        if (g == 0) {
            uint4 w;
            *(__half2*)&w.x = __float22half2_rn(make_float2(sn*h0, sn*h1));
            *(__half2*)&w.y = __float22half2_rn(make_float2(sn*h2, sn*h3));
            *(__half2*)&w.z = __float22half2_rn(make_float2(sn*h4, sn*h5));
            *(__half2*)&w.w = __float22half2_rn(make_float2(sn*h6, sn*h7));
            *(uint4*)(pnext + (size_t)node * DIM + t * 8) = w;
        }
    }
}

// fallback: scalar gather + out RMW (ignores CSR sentinel padding: loops p<c)
__global__ void gather_fb(const __half* __restrict__ pprev,
                          const float* __restrict__ src_norm, const float* __restrict__ dst_norm,
                          const int* __restrict__ cnt, const int* __restrict__ csr,
                          const float* __restrict__ s,
                          __half* __restrict__ pnext, float* __restrict__ out, int n) {
    int lane = threadIdx.x & 63;
    int wave = (blockIdx.x * blockDim.x + threadIdx.x) >> 6;
    int nwaves = (gridDim.x * blockDim.x) >> 6;
    float2 sv = *(const float2*)(s + lane * 2);
    for (int node = wave; node < n; node += nwaves) {
        int c = cnt[node]; if (c > CAP) c = CAP;
        const int* row = csr + (size_t)node * CAP;
        float accx = 0.0f, accy = 0.0f;
        for (int p = 0; p < c; ++p) {
            int si = row[p];
            float2 fv = __half22float2(*(const __half2*)(pprev + (size_t)si * DIM + lane * 2));
            accx += fv.x; accy += fv.y;
        }
        float dn = dst_norm[node];
        float hx = dn * accx, hy = dn * accy;
        float dot = hx * sv.x + hy * sv.y;
        #pragma unroll
        for (int off = 32; off > 0; off >>= 1) dot += __shfl_xor(dot, off);
        float sg = 1.0f / (1.0f + expf(-dot));
        float2 ov = *(float2*)(out + (size_t)node * DIM + lane * 2);
        ov.x += sg * hx; ov.y += sg * hy;
        *(float2*)(out + (size_t)node * DIM + lane * 2) = ov;
        float sn = src_norm[node];
        __half2 pw; pw.x = __float2half(sn * hx); pw.y = __float2half(sn * hy);
        *(__half2*)(pnext + (size_t)node * DIM + lane * 2) = pw;
    }
}

// flush: out[n] (+)= sum_{j=0..count-1} sg_{kstart+j}[n] * isrc[n] * p_{(kstart+j)%m}[n]
__global__ void out_accum(const __half* __restrict__ pbase, const float* __restrict__ sg,
                          const float* __restrict__ isrc, float* __restrict__ out,
                          int kstart, int count, int m, int first, int n) {
    int lane = threadIdx.x & 63;
    int wave = (blockIdx.x * blockDim.x + threadIdx.x) >> 6;
    int nwaves = (gridDim.x * blockDim.x) >> 6;
    for (int node = wave; node < n; node += nwaves) {
        float iv = isrc[node];
        float ax, ay;
        if (first) { ax = 0.0f; ay = 0.0f; }
        else {
            float2 ov = *(float2*)(out + (size_t)node * DIM + lane * 2);
            ax = ov.x; ay = ov.y;
        }
        for (int j = 0; j < count; ++j) {
            int kk = kstart + j;
            int slot = kk % m;
            float g = sg[(size_t)kk * n + node] * iv;
            float2 fv = __half22float2(
                *(const __half2*)(pbase + (size_t)slot * SLAB + (size_t)node * DIM + lane * 2));
            ax += g * fv.x; ay += g * fv.y;
        }
        *(float2*)(out + (size_t)node * DIM + lane * 2) = make_float2(ax, ay);
    }
}

extern "C" void kernel_launch(void* const* d_in, const int* in_sizes, int n_in,
                              void* d_out, int out_size, void* d_ws, size_t ws_size,
                              hipStream_t stream) {
    const float* feats = (const float*)d_in[0];
    const float* s     = (const float*)d_in[1];
    const int*   src   = (const int*)d_in[2];
    const int*   dst   = (const int*)d_in[3];
    float* out = (float*)d_out;
    const int E = in_sizes[2];

    // Workspace layout
    int*   outc     = (int*)d_ws;                         // N
    int*   cur      = outc + NODES;                       // N (in-degree after build)
    float* src_norm = (float*)(cur + NODES);              // N
    float* isrc     = src_norm + NODES;                   // N
    float* dst_norm = isrc + NODES;                       // N
    float* sg       = dst_norm + NODES;                   // 11*N
    int*   csr      = (int*)(sg + (size_t)(KSTEPS + 1) * NODES);   // N*CAP
    __half* pbase   = (__half*)(csr + (size_t)NODES * CAP);

    const size_t head_bytes = (size_t)(2 * NODES) * 4 + (size_t)(3 + KSTEPS + 1) * NODES * 4
                            + (size_t)NODES * CAP * 4;
    const size_t pbuf = SLAB * sizeof(__half);   // ~25.6 MB each (incl. sentinel row)

    // Ring size: how many p-slabs fit in the remaining workspace.
    int m = 0;
    if (ws_size > head_bytes) m = (int)((ws_size - head_bytes) / pbuf);
    if (m > KSTEPS + 1) m = KSTEPS + 1;

    // Bucket storage aliased over the first p-slabs (written before combine0).
    unsigned* gdc    = (unsigned*)pbase;
    unsigned* gsc    = gdc + 64;
    unsigned* dpairs = gsc + 64;
    unsigned* spairs = dpairs + (size_t)NR * GBCAP;

    hipMemsetAsync(gdc, 0, 2 * 64 * sizeof(unsigned), stream);
    const int nbatch = (E + BT - 1) / BT;
    bucket_agg<<<nbatch, 256, 0, stream>>>(src, dst, gdc, gsc, dpairs, spairs, E);
    degree_scatter<<<2 * NR, 256, 0, stream>>>(gdc, gsc, dpairs, spairs, cur, outc, csr);
    norm_kernel<<<(NODES + 255) / 256, 256, 0, stream>>>(outc, cur, src_norm, isrc, dst_norm, NODES);

    const int ngrid = (NODES * 64 + 255) / 256;
    if (m >= 2) {
        // Zero each slab's sentinel row (index NODES) once, after the build
        // (the bucket storage aliases this region until degree_scatter ends).
        for (int slot = 0; slot < m; ++slot)
            hipMemsetAsync(pbase + (size_t)slot * SLAB + (size_t)NODES * DIM, 0,
                           DIM * sizeof(__half), stream);

        combine0_main<<<ngrid, 256, 0, stream>>>(feats, s, src_norm, pbase, sg, NODES);
        int flushed = 0;    // ks [0, flushed) already folded into out
        int first = 1;
        for (int k = 1; k <= KSTEPS; ++k) {
            if (k - flushed >= m) {
                out_accum<<<ngrid, 256, 0, stream>>>(pbase, sg, isrc, out,
                                                     flushed, k - flushed, m, first, NODES);
                flushed = k; first = 0;
            }
            const __half* pprev = pbase + (size_t)((k - 1) % m) * SLAB;
            __half* pnext = pbase + (size_t)(k % m) * SLAB;
            gather_main<<<ngrid, 256, 0, stream>>>(pprev, src_norm, dst_norm, cur, csr, s,
                                                   pnext, sg + (size_t)k * NODES, NODES);
        }
        out_accum<<<ngrid, 256, 0, stream>>>(pbase, sg, isrc, out,
                                             flushed, KSTEPS + 1 - flushed, m, first, NODES);
    } else {
        // Emergency fallback (should not trigger).
        __half* pA = pbase;
        __half* pB = pbase + SLAB;
        combine0_fb<<<ngrid, 256, 0, stream>>>(feats, s, src_norm, pA, out, NODES);
        const __half* pcur = pA;
        for (int k = 1; k <= KSTEPS; ++k) {
            __half* pnext = (k & 1) ? pB : pA;
            gather_fb<<<ngrid, 256, 0, stream>>>(pcur, src_norm, dst_norm, cur, csr, s,
                                                 pnext, out, NODES);
            pcur = pnext;
        }
    }
}

// Round 6
// 1368.365 us; speedup vs baseline: 1.1194x; 1.0335x over previous
//
#include <hip/hip_runtime.h>
#include <hip/hip_fp16.h>

#define NODES 100000
#define DIM 128
#define KSTEPS 10
#define CAP 96           // CSR slot capacity; max in-degree ~Poisson(32), max ~65 (<11 sigma)

// Block-aggregated binning: NR coarse ranges of RANGE nodes.
#define RSHIFT 11
#define RANGE 2048                   // nodes per range (CSR window L2-resident)
#define NR 49                        // ceil(100000/2048)
#define GBCAP 72000                  // mean E/NR ~65.3K -> +26 sigma headroom
#define VPT 16                       // edges per thread per batch
#define BT (256 * VPT)               // 4096 edges per block-batch
#define DS_THREADS 1024              // degree_scatter block size (16 waves/CU)

// Slab stride: NODES rows + 1 zero sentinel row (for padded-CSR gather).
#define SLAB ((size_t)(NODES + 1) * DIM)

// ---------- build phase A: block-aggregated two-stream binning ----------
__global__ void bucket_agg(const int* __restrict__ src, const int* __restrict__ dst,
                           unsigned* __restrict__ gdc, unsigned* __restrict__ gsc,
                           unsigned* __restrict__ dpairs, unsigned* __restrict__ spairs, int E) {
    __shared__ unsigned dcnt[NR], scnt[NR], dbase[NR], sbase[NR];
    const int tid = threadIdx.x;
    if (tid < NR) { dcnt[tid] = 0; scnt[tid] = 0; }
    __syncthreads();

    const int base = blockIdx.x * BT;
    int dv[VPT], sv[VPT];
    unsigned rd[VPT], rs[VPT];
    #pragma unroll
    for (int j = 0; j < VPT; ++j) {
        int i = base + tid + j * 256;
        if (i < E) {
            int d_ = dst[i]; int s_ = src[i];
            dv[j] = d_; sv[j] = s_;
            rd[j] = atomicAdd(&dcnt[d_ >> RSHIFT], 1u);
            rs[j] = atomicAdd(&scnt[s_ >> RSHIFT], 1u);
        }
    }
    __syncthreads();
    if (tid < NR) {
        unsigned c = dcnt[tid];
        dbase[tid] = c ? atomicAdd(&gdc[tid], c) : 0u;
    } else if (tid >= 64 && tid < 64 + NR) {
        int b = tid - 64;
        unsigned c = scnt[b];
        sbase[b] = c ? atomicAdd(&gsc[b], c) : 0u;
    }
    __syncthreads();
    #pragma unroll
    for (int j = 0; j < VPT; ++j) {
        int i = base + tid + j * 256;
        if (i < E) {
            int d_ = dv[j]; int s_ = sv[j];
            int b = d_ >> RSHIFT;
            unsigned pos = dbase[b] + rd[j];
            if (pos < GBCAP)
                dpairs[(size_t)b * GBCAP + pos] =
                    ((unsigned)s_ << RSHIFT) | (unsigned)(d_ & (RANGE - 1));
            int bs = s_ >> RSHIFT;
            unsigned ps = sbase[bs] + rs[j];
            if (ps < GBCAP)
                spairs[(size_t)bs * GBCAP + ps] = (unsigned)(s_ & (RANGE - 1));
        }
    }
}

// ---------- build phase B: per-range CSR scatter + degrees ----------
// Latency-chain fix: 1024 threads/block (16 waves/CU) + unroll-by-8 batched
// loads (one VMEM clause of 8 independent pair loads, then 8 LDS-atomic+store).
// dst part pads each CSR row to a multiple of 8 with sentinel index NODES
// (points at a zeroed row in every p-slab) -> branch-free gather.
__global__ __launch_bounds__(DS_THREADS) void
degree_scatter(const unsigned* __restrict__ gdc, const unsigned* __restrict__ gsc,
               const unsigned* __restrict__ dpairs, const unsigned* __restrict__ spairs,
               int* __restrict__ cur, int* __restrict__ outc,
               int* __restrict__ csr) {
    __shared__ int ctr[RANGE];
    const int r = blockIdx.x >> 1;
    const int nodebase = r << RSHIFT;
    for (int i = threadIdx.x; i < RANGE; i += blockDim.x) ctr[i] = 0;
    __syncthreads();
    if ((blockIdx.x & 1) == 0) {
        int cnt = (int)gdc[r]; if (cnt > GBCAP) cnt = GBCAP;
        const unsigned* p = dpairs + (size_t)r * GBCAP;
        int i = threadIdx.x;
        for (; i + 7 * DS_THREADS < cnt; i += 8 * DS_THREADS) {
            unsigned v0 = p[i];
            unsigned v1 = p[i + 1 * DS_THREADS];
            unsigned v2 = p[i + 2 * DS_THREADS];
            unsigned v3 = p[i + 3 * DS_THREADS];
            unsigned v4 = p[i + 4 * DS_THREADS];
            unsigned v5 = p[i + 5 * DS_THREADS];
            unsigned v6 = p[i + 6 * DS_THREADS];
            unsigned v7 = p[i + 7 * DS_THREADS];
            #define DS_PUT(v) { \
                int dloc = (int)((v) & (RANGE - 1)); \
                int s_ = (int)((v) >> RSHIFT); \
                int slot = atomicAdd(&ctr[dloc], 1); \
                if (slot < CAP) csr[(size_t)(nodebase + dloc) * CAP + slot] = s_; }
            DS_PUT(v0) DS_PUT(v1) DS_PUT(v2) DS_PUT(v3)
            DS_PUT(v4) DS_PUT(v5) DS_PUT(v6) DS_PUT(v7)
        }
        for (; i < cnt; i += DS_THREADS) {
            unsigned v = p[i];
            DS_PUT(v)
            #undef DS_PUT
        }
        __syncthreads();
        for (int q = threadIdx.x; q < RANGE; q += blockDim.x) {
            int node = nodebase + q;
            if (node < NODES) {
                int c = ctr[q]; if (c > CAP) c = CAP;
                cur[node] = ctr[q];
                int cpad = (c + 7) & ~7; if (cpad > CAP) cpad = CAP;
                for (int w = c; w < cpad; ++w)
                    csr[(size_t)node * CAP + w] = NODES;   // sentinel -> zero row
            }
        }
    } else {
        int cnt = (int)gsc[r]; if (cnt > GBCAP) cnt = GBCAP;
        const unsigned* p = spairs + (size_t)r * GBCAP;
        int i = threadIdx.x;
        for (; i + 7 * DS_THREADS < cnt; i += 8 * DS_THREADS) {
            unsigned v0 = p[i];
            unsigned v1 = p[i + 1 * DS_THREADS];
            unsigned v2 = p[i + 2 * DS_THREADS];
            unsigned v3 = p[i + 3 * DS_THREADS];
            unsigned v4 = p[i + 4 * DS_THREADS];
            unsigned v5 = p[i + 5 * DS_THREADS];
            unsigned v6 = p[i + 6 * DS_THREADS];
            unsigned v7 = p[i + 7 * DS_THREADS];
            atomicAdd(&ctr[v0], 1); atomicAdd(&ctr[v1], 1);
            atomicAdd(&ctr[v2], 1); atomicAdd(&ctr[v3], 1);
            atomicAdd(&ctr[v4], 1); atomicAdd(&ctr[v5], 1);
            atomicAdd(&ctr[v6], 1); atomicAdd(&ctr[v7], 1);
        }
        for (; i < cnt; i += DS_THREADS)
            atomicAdd(&ctr[p[i]], 1);
        __syncthreads();
        for (int q = threadIdx.x; q < RANGE; q += blockDim.x) {
            int node = nodebase + q;
            if (node < NODES) outc[node] = ctr[q];
        }
    }
}

// norms: src_norm = rsqrt(max(outdeg,1)); isrc = 1/src_norm; dst_norm = rsqrt(max(indeg,1))
__global__ void norm_kernel(const int* __restrict__ outc, const int* __restrict__ inc,
                            float* __restrict__ src_norm, float* __restrict__ isrc,
                            float* __restrict__ dst_norm, int n) {
    int i = blockIdx.x * blockDim.x + threadIdx.x;
    if (i < n) {
        float od = fmaxf((float)outc[i], 1.0f);
        float id = fmaxf((float)inc[i], 1.0f);
        float sn = rsqrtf(od);
        src_norm[i] = sn;
        isrc[i] = sqrtf(od);
        dst_norm[i] = rsqrtf(id);
    }
}

// ring path k=0: sg0 = sigmoid(<feats,s>); p0 = src_norm * feats (fp16). No out write.
__global__ void combine0_main(const float* __restrict__ feats, const float* __restrict__ s,
                              const float* __restrict__ src_norm,
                              __half* __restrict__ p0, float* __restrict__ sg0, int n) {
    int lane = threadIdx.x & 63;
    int wave = (blockIdx.x * blockDim.x + threadIdx.x) >> 6;
    int nwaves = (gridDim.x * blockDim.x) >> 6;
    float2 sv = *(const float2*)(s + lane * 2);
    for (int node = wave; node < n; node += nwaves) {
        float2 hv = *(const float2*)(feats + (size_t)node * DIM + lane * 2);
        float sn = src_norm[node];
        __half2 ph; ph.x = __float2half(sn * hv.x); ph.y = __float2half(sn * hv.y);
        *(__half2*)(p0 + (size_t)node * DIM + lane * 2) = ph;
        float dot = hv.x * sv.x + hv.y * sv.y;
        #pragma unroll
        for (int off = 32; off > 0; off >>= 1) dot += __shfl_xor(dot, off);
        if (lane == 0) sg0[node] = 1.0f / (1.0f + expf(-dot));
    }
}

// fallback k=0: out = sigmoid(<feats,s>)*feats; p0 = src_norm*feats
__global__ void combine0_fb(const float* __restrict__ feats, const float* __restrict__ s,
                            const float* __restrict__ src_norm,
                            __half* __restrict__ p0, float* __restrict__ out, int n) {
    int lane = threadIdx.x & 63;
    int wave = (blockIdx.x * blockDim.x + threadIdx.x) >> 6;
    int nwaves = (gridDim.x * blockDim.x) >> 6;
    float2 sv = *(const float2*)(s + lane * 2);
    for (int node = wave; node < n; node += nwaves) {
        float2 hv = *(const float2*)(feats + (size_t)node * DIM + lane * 2);
        float sn = src_norm[node];
        __half2 ph; ph.x = __float2half(sn * hv.x); ph.y = __float2half(sn * hv.y);
        *(__half2*)(p0 + (size_t)node * DIM + lane * 2) = ph;
        float dot = hv.x * sv.x + hv.y * sv.y;
        #pragma unroll
        for (int off = 32; off > 0; off >>= 1) dot += __shfl_xor(dot, off);
        float sg = 1.0f / (1.0f + expf(-dot));
        float2 ov; ov.x = sg * hv.x; ov.y = sg * hv.y;
        *(float2*)(out + (size_t)node * DIM + lane * 2) = ov;
    }
}

// One wave per node, 4-rows-per-instruction gather.
// Lane layout: g = lane>>4 (edge sub-group), t = lane&15 (dims 8t..8t+7).
__global__ void gather_main(const __half* __restrict__ pprev,
                            const float* __restrict__ src_norm, const float* __restrict__ dst_norm,
                            const int* __restrict__ cnt, const int* __restrict__ csr,
                            const float* __restrict__ s,
                            __half* __restrict__ pnext, float* __restrict__ sgk, int n) {
    int lane = threadIdx.x & 63;
    int g = lane >> 4, t = lane & 15;
    int wave = (blockIdx.x * blockDim.x + threadIdx.x) >> 6;
    int nwaves = (gridDim.x * blockDim.x) >> 6;
    float4 sva = *(const float4*)(s + t * 8);
    float4 svb = *(const float4*)(s + t * 8 + 4);
    for (int node = wave; node < n; node += nwaves) {
        int c = cnt[node]; if (c > CAP) c = CAP;
        int cpad = (c + 7) & ~7;
        const int* row = csr + (size_t)node * CAP;
        float a0=0,a1=0,a2=0,a3=0,a4=0,a5=0,a6=0,a7=0;
        int p = 0;
        for (; p + 15 < cpad; p += 16) {
            int e0 = row[p + g];
            int e1 = row[p + 4 + g];
            int e2 = row[p + 8 + g];
            int e3 = row[p + 12 + g];
            uint4 q0 = *(const uint4*)(pprev + (size_t)e0 * DIM + t * 8);
            uint4 q1 = *(const uint4*)(pprev + (size_t)e1 * DIM + t * 8);
            uint4 q2 = *(const uint4*)(pprev + (size_t)e2 * DIM + t * 8);
            uint4 q3 = *(const uint4*)(pprev + (size_t)e3 * DIM + t * 8);
            float2 f;
            f = __half22float2(*(__half2*)&q0.x); a0+=f.x; a1+=f.y;
            f = __half22float2(*(__half2*)&q0.y); a2+=f.x; a3+=f.y;
            f = __half22float2(*(__half2*)&q0.z); a4+=f.x; a5+=f.y;
            f = __half22float2(*(__half2*)&q0.w); a6+=f.x; a7+=f.y;
            f = __half22float2(*(__half2*)&q1.x); a0+=f.x; a1+=f.y;
            f = __half22float2(*(__half2*)&q1.y); a2+=f.x; a3+=f.y;
            f = __half22float2(*(__half2*)&q1.z); a4+=f.x; a5+=f.y;
            f = __half22float2(*(__half2*)&q1.w); a6+=f.x; a7+=f.y;
            f = __half22float2(*(__half2*)&q2.x); a0+=f.x; a1+=f.y;
            f = __half22float2(*(__half2*)&q2.y); a2+=f.x; a3+=f.y;
            f = __half22float2(*(__half2*)&q2.z); a4+=f.x; a5+=f.y;
            f = __half22float2(*(__half2*)&q2.w); a6+=f.x; a7+=f.y;
            f = __half22float2(*(__half2*)&q3.x); a0+=f.x; a1+=f.y;
            f = __half22float2(*(__half2*)&q3.y); a2+=f.x; a3+=f.y;
            f = __half22float2(*(__half2*)&q3.z); a4+=f.x; a5+=f.y;
            f = __half22float2(*(__half2*)&q3.w); a6+=f.x; a7+=f.y;
        }
        for (; p < cpad; p += 8) {
            int e0 = row[p + g];
            int e1 = row[p + 4 + g];
            uint4 q0 = *(const uint4*)(pprev + (size_t)e0 * DIM + t * 8);
            uint4 q1 = *(const uint4*)(pprev + (size_t)e1 * DIM + t * 8);
            float2 f;
            f = __half22float2(*(__half2*)&q0.x); a0+=f.x; a1+=f.y;
            f = __half22float2(*(__half2*)&q0.y); a2+=f.x; a3+=f.y;
            f = __half22float2(*(__half2*)&q0.z); a4+=f.x; a5+=f.y;
            f = __half22float2(*(__half2*)&q0.w); a6+=f.x; a7+=f.y;
            f = __half22float2(*(__half2*)&q1.x); a0+=f.x; a1+=f.y;
            f = __half22float2(*(__half2*)&q1.y); a2+=f.x; a3+=f.y;
            f = __half22float2(*(__half2*)&q1.z); a4+=f.x; a5+=f.y;
            f = __half22float2(*(__half2*)&q1.w); a6+=f.x; a7+=f.y;
        }
        a0 += __shfl_xor(a0, 16); a0 += __shfl_xor(a0, 32);
        a1 += __shfl_xor(a1, 16); a1 += __shfl_xor(a1, 32);
        a2 += __shfl_xor(a2, 16); a2 += __shfl_xor(a2, 32);
        a3 += __shfl_xor(a3, 16); a3 += __shfl_xor(a3, 32);
        a4 += __shfl_xor(a4, 16); a4 += __shfl_xor(a4, 32);
        a5 += __shfl_xor(a5, 16); a5 += __shfl_xor(a5, 32);
        a6 += __shfl_xor(a6, 16); a6 += __shfl_xor(a6, 32);
        a7 += __shfl_xor(a7, 16); a7 += __shfl_xor(a7, 32);
        float dn = dst_norm[node];
        float h0=dn*a0, h1=dn*a1, h2=dn*a2, h3=dn*a3;
        float h4=dn*a4, h5=dn*a5, h6=dn*a6, h7=dn*a7;
        float dot = h0*sva.x + h1*sva.y + h2*sva.z + h3*sva.w
                  + h4*svb.x + h5*svb.y + h6*svb.z + h7*svb.w;
        dot += __shfl_xor(dot, 1); dot += __shfl_xor(dot, 2);
        dot += __shfl_xor(dot, 4); dot += __shfl_xor(dot, 8);
        if (lane == 0) sgk[node] = 1.0f / (1.0f + expf(-dot));
        float sn = src_norm[node];
        if (g == 0) {
            uint4 w;
            *(__half2*)&w.x = __float22half2_rn(make_float2(sn*h0, sn*h1));
            *(__half2*)&w.y = __float22half2_rn(make_float2(sn*h2, sn*h3));
            *(__half2*)&w.z = __float22half2_rn(make_float2(sn*h4, sn*h5));
            *(__half2*)&w.w = __float22half2_rn(make_float2(sn*h6, sn*h7));
            *(uint4*)(pnext + (size_t)node * DIM + t * 8) = w;
        }
    }
}

// fallback: scalar gather + out RMW (ignores CSR sentinel padding: loops p<c)
__global__ void gather_fb(const __half* __restrict__ pprev,
                          const float* __restrict__ src_norm, const float* __restrict__ dst_norm,
                          const int* __restrict__ cnt, const int* __restrict__ csr,
                          const float* __restrict__ s,
                          __half* __restrict__ pnext, float* __restrict__ out, int n) {
    int lane = threadIdx.x & 63;
    int wave = (blockIdx.x * blockDim.x + threadIdx.x) >> 6;
    int nwaves = (gridDim.x * blockDim.x) >> 6;
    float2 sv = *(const float2*)(s + lane * 2);
    for (int node = wave; node < n; node += nwaves) {
        int c = cnt[node]; if (c > CAP) c = CAP;
        const int* row = csr + (size_t)node * CAP;
        float accx = 0.0f, accy = 0.0f;
        for (int p = 0; p < c; ++p) {
            int si = row[p];
            float2 fv = __half22float2(*(const __half2*)(pprev + (size_t)si * DIM + lane * 2));
            accx += fv.x; accy += fv.y;
        }
        float dn = dst_norm[node];
        float hx = dn * accx, hy = dn * accy;
        float dot = hx * sv.x + hy * sv.y;
        #pragma unroll
        for (int off = 32; off > 0; off >>= 1) dot += __shfl_xor(dot, off);
        float sg = 1.0f / (1.0f + expf(-dot));
        float2 ov = *(float2*)(out + (size_t)node * DIM + lane * 2);
        ov.x += sg * hx; ov.y += sg * hy;
        *(float2*)(out + (size_t)node * DIM + lane * 2) = ov;
        float sn = src_norm[node];
        __half2 pw; pw.x = __float2half(sn * hx); pw.y = __float2half(sn * hy);
        *(__half2*)(pnext + (size_t)node * DIM + lane * 2) = pw;
    }
}

// flush: out[n] (+)= sum_{j=0..count-1} sg_{kstart+j}[n] * isrc[n] * p_{(kstart+j)%m}[n]
__global__ void out_accum(const __half* __restrict__ pbase, const float* __restrict__ sg,
                          const float* __restrict__ isrc, float* __restrict__ out,
                          int kstart, int count, int m, int first, int n) {
    int lane = threadIdx.x & 63;
    int wave = (blockIdx.x * blockDim.x + threadIdx.x) >> 6;
    int nwaves = (gridDim.x * blockDim.x) >> 6;
    for (int node = wave; node < n; node += nwaves) {
        float iv = isrc[node];
        float ax, ay;
        if (first) { ax = 0.0f; ay = 0.0f; }
        else {
            float2 ov = *(float2*)(out + (size_t)node * DIM + lane * 2);
            ax = ov.x; ay = ov.y;
        }
        for (int j = 0; j < count; ++j) {
            int kk = kstart + j;
            int slot = kk % m;
            float g = sg[(size_t)kk * n + node] * iv;
            float2 fv = __half22float2(
                *(const __half2*)(pbase + (size_t)slot * SLAB + (size_t)node * DIM + lane * 2));
            ax += g * fv.x; ay += g * fv.y;
        }
        *(float2*)(out + (size_t)node * DIM + lane * 2) = make_float2(ax, ay);
    }
}

extern "C" void kernel_launch(void* const* d_in, const int* in_sizes, int n_in,
                              void* d_out, int out_size, void* d_ws, size_t ws_size,
                              hipStream_t stream) {
    const float* feats = (const float*)d_in[0];
    const float* s     = (const float*)d_in[1];
    const int*   src   = (const int*)d_in[2];
    const int*   dst   = (const int*)d_in[3];
    float* out = (float*)d_out;
    const int E = in_sizes[2];

    // Workspace layout
    int*   outc     = (int*)d_ws;                         // N
    int*   cur      = outc + NODES;                       // N (in-degree after build)
    float* src_norm = (float*)(cur + NODES);              // N
    float* isrc     = src_norm + NODES;                   // N
    float* dst_norm = isrc + NODES;                       // N
    float* sg       = dst_norm + NODES;                   // 11*N
    int*   csr      = (int*)(sg + (size_t)(KSTEPS + 1) * NODES);   // N*CAP
    __half* pbase   = (__half*)(csr + (size_t)NODES * CAP);

    const size_t head_bytes = (size_t)(2 * NODES) * 4 + (size_t)(3 + KSTEPS + 1) * NODES * 4
                            + (size_t)NODES * CAP * 4;
    const size_t pbuf = SLAB * sizeof(__half);   // ~25.6 MB each (incl. sentinel row)

    // Ring size: how many p-slabs fit in the remaining workspace.
    int m = 0;
    if (ws_size > head_bytes) m = (int)((ws_size - head_bytes) / pbuf);
    if (m > KSTEPS + 1) m = KSTEPS + 1;

    // Bucket storage aliased over the first p-slabs (written before combine0).
    unsigned* gdc    = (unsigned*)pbase;
    unsigned* gsc    = gdc + 64;
    unsigned* dpairs = gsc + 64;
    unsigned* spairs = dpairs + (size_t)NR * GBCAP;

    hipMemsetAsync(gdc, 0, 2 * 64 * sizeof(unsigned), stream);
    const int nbatch = (E + BT - 1) / BT;
    bucket_agg<<<nbatch, 256, 0, stream>>>(src, dst, gdc, gsc, dpairs, spairs, E);
    degree_scatter<<<2 * NR, DS_THREADS, 0, stream>>>(gdc, gsc, dpairs, spairs, cur, outc, csr);
    norm_kernel<<<(NODES + 255) / 256, 256, 0, stream>>>(outc, cur, src_norm, isrc, dst_norm, NODES);

    const int ngrid = (NODES * 64 + 255) / 256;
    if (m >= 2) {
        // Zero each slab's sentinel row (index NODES) once, after the build
        // (the bucket storage aliases this region until degree_scatter ends).
        for (int slot = 0; slot < m; ++slot)
            hipMemsetAsync(pbase + (size_t)slot * SLAB + (size_t)NODES * DIM, 0,
                           DIM * sizeof(__half), stream);

        combine0_main<<<ngrid, 256, 0, stream>>>(feats, s, src_norm, pbase, sg, NODES);
        int flushed = 0;    // ks [0, flushed) already folded into out
        int first = 1;
        for (int k = 1; k <= KSTEPS; ++k) {
            if (k - flushed >= m) {
                out_accum<<<ngrid, 256, 0, stream>>>(pbase, sg, isrc, out,
                                                     flushed, k - flushed, m, first, NODES);
                flushed = k; first = 0;
            }
            const __half* pprev = pbase + (size_t)((k - 1) % m) * SLAB;
            __half* pnext = pbase + (size_t)(k % m) * SLAB;
            gather_main<<<ngrid, 256, 0, stream>>>(pprev, src_norm, dst_norm, cur, csr, s,
                                                   pnext, sg + (size_t)k * NODES, NODES);
        }
        out_accum<<<ngrid, 256, 0, stream>>>(pbase, sg, isrc, out,
                                             flushed, KSTEPS + 1 - flushed, m, first, NODES);
    } else {
        // Emergency fallback (should not trigger).
        __half* pA = pbase;
        __half* pB = pbase + SLAB;
        combine0_fb<<<ngrid, 256, 0, stream>>>(feats, s, src_norm, pA, out, NODES);
        const __half* pcur = pA;
        for (int k = 1; k <= KSTEPS; ++k) {
            __half* pnext = (k & 1) ? pB : pA;
            gather_fb<<<ngrid, 256, 0, stream>>>(pcur, src_norm, dst_norm, cur, csr, s,
                                                 pnext, out, NODES);
            pcur = pnext;
        }
    }
}